// Round 2
// baseline (3679.088 us; speedup 1.0000x reference)
//
#include <hip/hip_runtime.h>
#include <hip/hip_bf16.h>

#define NUM_USERS 100000
#define NUM_ITEMS 50000
#define N_NODES   150000
#define DIM       64
#define N_LAYERS  3
#define N_QU      1024
#define N_QI      20000

// ---------------------------------------------------------------------------
// init: acc = h = concat(user_emb, item_emb), vectorized float4
// ---------------------------------------------------------------------------
__global__ void init_nodes(const float* __restrict__ ue, const float* __restrict__ ie,
                           float* __restrict__ acc, float* __restrict__ h) {
    const size_t n4   = (size_t)N_NODES * DIM / 4;      // 2.4M float4
    const size_t uend = (size_t)NUM_USERS * DIM / 4;    // 1.6M float4
    const float4* ue4 = (const float4*)ue;
    const float4* ie4 = (const float4*)ie;
    float4* acc4 = (float4*)acc;
    float4* h4   = (float4*)h;
    size_t stride = (size_t)gridDim.x * blockDim.x;
    for (size_t i = (size_t)blockIdx.x * blockDim.x + threadIdx.x; i < n4; i += stride) {
        float4 v = (i < uend) ? ue4[i] : ie4[i - uend];
        acc4[i] = v;
        h4[i]   = v;
    }
}

// ---------------------------------------------------------------------------
// spmm: y[dst] += val * x[src]  (y must be pre-zeroed)
// one wave (64 lanes) per edge, lane = dim; edge params loaded coalesced in
// chunks of 64 and broadcast via __shfl.
// ---------------------------------------------------------------------------
__global__ __launch_bounds__(256) void spmm_atomic(
        const int* __restrict__ src, const int* __restrict__ dst,
        const float* __restrict__ vals, const float* __restrict__ x,
        float* __restrict__ y, int n_edges) {
    int lane   = threadIdx.x & 63;
    int wave   = (int)((blockIdx.x * blockDim.x + threadIdx.x) >> 6);
    int nwaves = (int)((gridDim.x * blockDim.x) >> 6);

    for (int base = wave * 64; base < n_edges; base += nwaves * 64) {
        int e = base + lane;
        int s = 0, d = 0; float v = 0.0f;
        if (e < n_edges) { s = src[e]; d = dst[e]; v = vals[e]; }
        int cnt = n_edges - base; if (cnt > 64) cnt = 64;
        for (int k = 0; k < cnt; ++k) {
            int   sk = __shfl(s, k);
            int   dk = __shfl(d, k);
            float vk = __shfl(v, k);
            float xv = x[(size_t)sk * DIM + lane];
            unsafeAtomicAdd(&y[(size_t)dk * DIM + lane], vk * xv);
        }
    }
}

// ---------------------------------------------------------------------------
// acc += h, vectorized
// ---------------------------------------------------------------------------
__global__ void add_acc(float* __restrict__ acc, const float* __restrict__ h) {
    const size_t n4 = (size_t)N_NODES * DIM / 4;
    float4* a4 = (float4*)acc;
    const float4* h4 = (const float4*)h;
    size_t stride = (size_t)gridDim.x * blockDim.x;
    for (size_t i = (size_t)blockIdx.x * blockDim.x + threadIdx.x; i < n4; i += stride) {
        float4 a = a4[i], b = h4[i];
        a.x += b.x; a.y += b.y; a.z += b.z; a.w += b.w;
        a4[i] = a;
    }
}

// ---------------------------------------------------------------------------
// ratings = sigmoid( (acc[users]/4) @ (acc[100000+items]/4)^T )
// 64x64 tile per 256-thread block, 4x4 register micro-tile per thread.
// 0.25 scale folded into each LDS tile (0.25^2 = 1/16 = /4 per operand).
// ---------------------------------------------------------------------------
__global__ __launch_bounds__(256) void rating_kernel(
        const float* __restrict__ acc, const int* __restrict__ users,
        const int* __restrict__ items, float* __restrict__ out) {
    __shared__ float U[64][65];
    __shared__ float T[64][65];
    int bj = blockIdx.x;   // item tile (j)
    int bi = blockIdx.y;   // user tile (i)
    int t  = threadIdx.x;

    for (int idx = t; idx < 64 * 64; idx += 256) {
        int r = idx >> 6, k = idx & 63;
        int u = users[bi * 64 + r];
        U[r][k] = acc[(size_t)u * DIM + k] * 0.25f;
    }
    for (int idx = t; idx < 64 * 64; idx += 256) {
        int r = idx >> 6, k = idx & 63;
        int jg = bj * 64 + r;
        float v = 0.0f;
        if (jg < N_QI) {
            int it = items[jg];
            v = acc[((size_t)(NUM_USERS + it)) * DIM + k] * 0.25f;
        }
        T[r][k] = v;
    }
    __syncthreads();

    int tr = t >> 4, tc = t & 15;
    float c[4][4] = {};
    #pragma unroll
    for (int k = 0; k < 64; ++k) {
        float ua[4], tb[4];
        #pragma unroll
        for (int a = 0; a < 4; ++a) ua[a] = U[tr * 4 + a][k];
        #pragma unroll
        for (int b = 0; b < 4; ++b) tb[b] = T[tc * 4 + b][k];
        #pragma unroll
        for (int a = 0; a < 4; ++a)
            #pragma unroll
            for (int b = 0; b < 4; ++b)
                c[a][b] += ua[a] * tb[b];
    }

    #pragma unroll
    for (int a = 0; a < 4; ++a) {
        int i = bi * 64 + tr * 4 + a;
        int j = bj * 64 + tc * 4;
        if (j < N_QI) {
            float4 r;
            r.x = 1.0f / (1.0f + __expf(-c[a][0]));
            r.y = 1.0f / (1.0f + __expf(-c[a][1]));
            r.z = 1.0f / (1.0f + __expf(-c[a][2]));
            r.w = 1.0f / (1.0f + __expf(-c[a][3]));
            *(float4*)&out[(size_t)i * N_QI + j] = r;
        }
    }
}

// ---------------------------------------------------------------------------
extern "C" void kernel_launch(void* const* d_in, const int* in_sizes, int n_in,
                              void* d_out, int out_size, void* d_ws, size_t ws_size,
                              hipStream_t stream) {
    const float* user_emb  = (const float*)d_in[0];
    const float* item_emb  = (const float*)d_in[1];
    const int*   edge_src  = (const int*)d_in[2];
    const int*   edge_dst  = (const int*)d_in[3];
    const float* edge_vals = (const float*)d_in[4];
    const int*   users     = (const int*)d_in[5];
    const int*   items     = (const int*)d_in[6];
    float*       out       = (float*)d_out;
    int n_edges = in_sizes[2];

    const size_t nodeElems = (size_t)N_NODES * DIM;   // 9.6M floats
    float* acc = (float*)d_ws;
    float* hA  = acc + nodeElems;
    float* hB  = hA + nodeElems;

    init_nodes<<<2048, 256, 0, stream>>>(user_emb, item_emb, acc, hA);

    float* cur = hA;
    float* nxt = hB;
    for (int l = 0; l < N_LAYERS; ++l) {
        hipMemsetAsync(nxt, 0, nodeElems * sizeof(float), stream);
        spmm_atomic<<<1024, 256, 0, stream>>>(edge_src, edge_dst, edge_vals, cur, nxt, n_edges);
        add_acc<<<2048, 256, 0, stream>>>(acc, nxt);
        float* tmp = cur; cur = nxt; nxt = tmp;
    }

    dim3 grid((N_QI + 63) / 64, N_QU / 64);
    rating_kernel<<<grid, 256, 0, stream>>>(acc, users, items, out);
}

// Round 4
// 1857.352 us; speedup vs baseline: 1.9808x; 1.9808x over previous
//
#include <hip/hip_runtime.h>
#include <hip/hip_bf16.h>

#define NUM_USERS 100000
#define NUM_ITEMS 50000
#define N_NODES   150000
#define DIM       64
#define N_LAYERS  3
#define N_QU      1024
#define N_QI      20000

// ---------------------------------------------------------------------------
// init: acc = h = concat(user_emb, item_emb), vectorized float4
// ---------------------------------------------------------------------------
__global__ void init_nodes(const float* __restrict__ ue, const float* __restrict__ ie,
                           float* __restrict__ acc, float* __restrict__ h) {
    const size_t n4   = (size_t)N_NODES * DIM / 4;
    const size_t uend = (size_t)NUM_USERS * DIM / 4;
    const float4* ue4 = (const float4*)ue;
    const float4* ie4 = (const float4*)ie;
    float4* acc4 = (float4*)acc;
    float4* h4   = (float4*)h;
    size_t stride = (size_t)gridDim.x * blockDim.x;
    for (size_t i = (size_t)blockIdx.x * blockDim.x + threadIdx.x; i < n4; i += stride) {
        float4 v = (i < uend) ? ue4[i] : ie4[i - uend];
        acc4[i] = v;
        h4[i]   = v;
    }
}

// ---------------------------------------------------------------------------
// CSR build step 1: degree histogram
// ---------------------------------------------------------------------------
__global__ void hist_kernel(const int* __restrict__ dst, int* __restrict__ deg, int n) {
    int stride = gridDim.x * blockDim.x;
    for (int i = blockIdx.x * blockDim.x + threadIdx.x; i < n; i += stride)
        atomicAdd(&deg[dst[i]], 1);
}

// ---------------------------------------------------------------------------
// CSR build step 2: exclusive scan of degrees (single block, 1024 threads,
// each thread owns a contiguous chunk of 147 nodes).
// ---------------------------------------------------------------------------
__global__ __launch_bounds__(1024) void scan_kernel(const int* __restrict__ deg,
        int* __restrict__ row_ptr, int* __restrict__ cursor) {
    __shared__ int part[1024];
    int t = threadIdx.x;
    const int CH = (N_NODES + 1023) / 1024;   // 147
    int begin = t * CH;
    int end   = begin + CH;
    if (begin > N_NODES) begin = N_NODES;
    if (end   > N_NODES) end   = N_NODES;
    int s = 0;
    for (int i = begin; i < end; ++i) s += deg[i];
    part[t] = s;
    __syncthreads();
    int x = s;
    for (int off = 1; off < 1024; off <<= 1) {
        int y = (t >= off) ? part[t - off] : 0;
        __syncthreads();
        x += y;
        part[t] = x;
        __syncthreads();
    }
    int run = x - s;   // exclusive prefix of this thread's chunk
    for (int i = begin; i < end; ++i) {
        row_ptr[i] = run;
        cursor[i]  = run;
        run += deg[i];
    }
    if (t == 1023) row_ptr[N_NODES] = run;
}

// ---------------------------------------------------------------------------
// CSR build step 3: scatter edges into per-dst buckets, packed (src, val)
// ---------------------------------------------------------------------------
__global__ void scatter_kernel(const int* __restrict__ src, const int* __restrict__ dst,
        const float* __restrict__ vals, int* __restrict__ cursor,
        int2* __restrict__ packed, int n) {
    int stride = gridDim.x * blockDim.x;
    for (int i = blockIdx.x * blockDim.x + threadIdx.x; i < n; i += stride) {
        int p = atomicAdd(&cursor[dst[i]], 1);
        packed[p] = make_int2(src[i], __float_as_int(vals[i]));
    }
}

// ---------------------------------------------------------------------------
// SpMM gather: one wave per dst node, lane = dim. Register accumulation,
// zero atomics, single write per output row. acc += fused into the epilogue.
// ---------------------------------------------------------------------------
__global__ __launch_bounds__(256) void spmm_gather(
        const int* __restrict__ row_ptr, const int2* __restrict__ packed,
        const float* __restrict__ x, float* __restrict__ y,
        float* __restrict__ acc) {
    int lane   = threadIdx.x & 63;
    int wave   = (int)((blockIdx.x * blockDim.x + threadIdx.x) >> 6);
    int nwaves = (int)((gridDim.x * blockDim.x) >> 6);

    for (int node = wave; node < N_NODES; node += nwaves) {
        int beg = row_ptr[node];
        int end = row_ptr[node + 1];
        float r = 0.0f;
        for (int base = beg; base < end; base += 64) {
            int e = base + lane;
            int2 pk = (e < end) ? packed[e] : make_int2(0, 0);
            int cnt = end - base; if (cnt > 64) cnt = 64;
            for (int k = 0; k < cnt; ++k) {
                int   sk = __shfl(pk.x, k);
                float vk = __int_as_float(__shfl(pk.y, k));
                r += vk * x[(size_t)sk * DIM + lane];
            }
        }
        size_t o = (size_t)node * DIM + lane;
        y[o] = r;
        acc[o] += r;
    }
}

// ---------------------------------------------------------------------------
// ratings = sigmoid( (acc[users]/4) @ (acc[100000+items]/4)^T )
// ---------------------------------------------------------------------------
__global__ __launch_bounds__(256) void rating_kernel(
        const float* __restrict__ acc, const int* __restrict__ users,
        const int* __restrict__ items, float* __restrict__ out) {
    __shared__ float U[64][65];
    __shared__ float T[64][65];
    int bj = blockIdx.x;
    int bi = blockIdx.y;
    int t  = threadIdx.x;

    for (int idx = t; idx < 64 * 64; idx += 256) {
        int r = idx >> 6, k = idx & 63;
        int u = users[bi * 64 + r];
        U[r][k] = acc[(size_t)u * DIM + k] * 0.25f;
    }
    for (int idx = t; idx < 64 * 64; idx += 256) {
        int r = idx >> 6, k = idx & 63;
        int jg = bj * 64 + r;
        float v = 0.0f;
        if (jg < N_QI) {
            int it = items[jg];
            v = acc[((size_t)(NUM_USERS + it)) * DIM + k] * 0.25f;
        }
        T[r][k] = v;
    }
    __syncthreads();

    int tr = t >> 4, tc = t & 15;
    float c[4][4] = {};
    #pragma unroll
    for (int k = 0; k < 64; ++k) {
        float ua[4], tb[4];
        #pragma unroll
        for (int a = 0; a < 4; ++a) ua[a] = U[tr * 4 + a][k];
        #pragma unroll
        for (int b = 0; b < 4; ++b) tb[b] = T[tc * 4 + b][k];
        #pragma unroll
        for (int a = 0; a < 4; ++a)
            #pragma unroll
            for (int b = 0; b < 4; ++b)
                c[a][b] += ua[a] * tb[b];
    }

    #pragma unroll
    for (int a = 0; a < 4; ++a) {
        int i = bi * 64 + tr * 4 + a;
        int j = bj * 64 + tc * 4;
        if (j < N_QI) {
            float4 r;
            r.x = 1.0f / (1.0f + __expf(-c[a][0]));
            r.y = 1.0f / (1.0f + __expf(-c[a][1]));
            r.z = 1.0f / (1.0f + __expf(-c[a][2]));
            r.w = 1.0f / (1.0f + __expf(-c[a][3]));
            *(float4*)&out[(size_t)i * N_QI + j] = r;
        }
    }
}

// ---------------------------------------------------------------------------
extern "C" void kernel_launch(void* const* d_in, const int* in_sizes, int n_in,
                              void* d_out, int out_size, void* d_ws, size_t ws_size,
                              hipStream_t stream) {
    const float* user_emb  = (const float*)d_in[0];
    const float* item_emb  = (const float*)d_in[1];
    const int*   edge_src  = (const int*)d_in[2];
    const int*   edge_dst  = (const int*)d_in[3];
    const float* edge_vals = (const float*)d_in[4];
    const int*   users     = (const int*)d_in[5];
    const int*   items     = (const int*)d_in[6];
    float*       out       = (float*)d_out;
    int n_edges = in_sizes[2];

    const size_t nodeElems = (size_t)N_NODES * DIM;   // 9.6M floats

    float* acc    = (float*)d_ws;                     // 38.4 MB
    float* hA     = acc + nodeElems;                  // 38.4 MB
    float* hB     = hA + nodeElems;                   // 38.4 MB
    int2*  packed = (int2*)(hB + nodeElems);          // 38.4 MB (4.8M int2)
    int*   row_ptr = (int*)(packed + n_edges);        // 150001 ints
    int*   deg     = row_ptr + (N_NODES + 1);         // 150000 ints
    int*   cursor  = deg + N_NODES;                   // 150000 ints

    // --- CSR build (amortized over 3 layers) ---
    (void)hipMemsetAsync(deg, 0, (size_t)N_NODES * sizeof(int), stream);
    init_nodes<<<2048, 256, 0, stream>>>(user_emb, item_emb, acc, hA);
    hist_kernel<<<2048, 256, 0, stream>>>(edge_dst, deg, n_edges);
    scan_kernel<<<1, 1024, 0, stream>>>(deg, row_ptr, cursor);
    scatter_kernel<<<2048, 256, 0, stream>>>(edge_src, edge_dst, edge_vals,
                                             cursor, packed, n_edges);

    // --- 3 propagation layers, acc += fused ---
    float* cur = hA;
    float* nxt = hB;
    for (int l = 0; l < N_LAYERS; ++l) {
        spmm_gather<<<2048, 256, 0, stream>>>(row_ptr, packed, cur, nxt, acc);
        float* tmp = cur; cur = nxt; nxt = tmp;
    }

    // --- ratings ---
    dim3 grid((N_QI + 63) / 64, N_QU / 64);
    rating_kernel<<<grid, 256, 0, stream>>>(acc, users, items, out);
}

// Round 5
// 1678.200 us; speedup vs baseline: 2.1923x; 1.1068x over previous
//
#include <hip/hip_runtime.h>
#include <hip/hip_bf16.h>

#define NUM_USERS 100000
#define NUM_ITEMS 50000
#define N_NODES   150000
#define DIM       64
#define N_LAYERS  3
#define N_QU      1024
#define N_QI      20000
#define N_SCATTER_PASSES 8

// ---------------------------------------------------------------------------
// init: acc = h = concat(user_emb, item_emb), vectorized float4
// ---------------------------------------------------------------------------
__global__ void init_nodes(const float* __restrict__ ue, const float* __restrict__ ie,
                           float* __restrict__ acc, float* __restrict__ h) {
    const size_t n4   = (size_t)N_NODES * DIM / 4;
    const size_t uend = (size_t)NUM_USERS * DIM / 4;
    const float4* ue4 = (const float4*)ue;
    const float4* ie4 = (const float4*)ie;
    float4* acc4 = (float4*)acc;
    float4* h4   = (float4*)h;
    size_t stride = (size_t)gridDim.x * blockDim.x;
    for (size_t i = (size_t)blockIdx.x * blockDim.x + threadIdx.x; i < n4; i += stride) {
        float4 v = (i < uend) ? ue4[i] : ie4[i - uend];
        acc4[i] = v;
        h4[i]   = v;
    }
}

// ---------------------------------------------------------------------------
// CSR build step 1: degree histogram (int4-vectorized edge reads)
// ---------------------------------------------------------------------------
__global__ void hist_kernel(const int* __restrict__ dst, int* __restrict__ deg, int n) {
    int stride = gridDim.x * blockDim.x;
    int n4 = n >> 2;
    const int4* d4 = (const int4*)dst;
    for (int i = blockIdx.x * blockDim.x + threadIdx.x; i < n4; i += stride) {
        int4 d = d4[i];
        atomicAdd(&deg[d.x], 1);
        atomicAdd(&deg[d.y], 1);
        atomicAdd(&deg[d.z], 1);
        atomicAdd(&deg[d.w], 1);
    }
    // tail
    for (int i = (n4 << 2) + blockIdx.x * blockDim.x + threadIdx.x; i < n; i += stride)
        atomicAdd(&deg[dst[i]], 1);
}

// ---------------------------------------------------------------------------
// CSR build step 2: exclusive scan of degrees (single block, 1024 threads)
// ---------------------------------------------------------------------------
__global__ __launch_bounds__(1024) void scan_kernel(const int* __restrict__ deg,
        int* __restrict__ row_ptr, int* __restrict__ cursor) {
    __shared__ int part[1024];
    int t = threadIdx.x;
    const int CH = (N_NODES + 1023) / 1024;   // 147
    int begin = t * CH;
    int end   = begin + CH;
    if (begin > N_NODES) begin = N_NODES;
    if (end   > N_NODES) end   = N_NODES;
    int s = 0;
    for (int i = begin; i < end; ++i) s += deg[i];
    part[t] = s;
    __syncthreads();
    int x = s;
    for (int off = 1; off < 1024; off <<= 1) {
        int y = (t >= off) ? part[t - off] : 0;
        __syncthreads();
        x += y;
        part[t] = x;
        __syncthreads();
    }
    int run = x - s;   // exclusive prefix of this thread's chunk
    for (int i = begin; i < end; ++i) {
        row_ptr[i] = run;
        cursor[i]  = run;
        run += deg[i];
    }
    if (t == 1023) row_ptr[N_NODES] = run;
}

// ---------------------------------------------------------------------------
// CSR build step 3: range-partitioned scatter. Only edges with dst in
// [lo, hi) are scattered this pass -> the 4.8 MB write window stays
// L2-resident so partially-written lines fill before eviction.
// ---------------------------------------------------------------------------
__global__ void scatter_kernel(const int* __restrict__ src, const int* __restrict__ dst,
        const float* __restrict__ vals, int* __restrict__ cursor,
        int2* __restrict__ packed, int n, int lo, int hi) {
    int stride = gridDim.x * blockDim.x;
    int n4 = n >> 2;
    const int4* d4 = (const int4*)dst;
    for (int i = blockIdx.x * blockDim.x + threadIdx.x; i < n4; i += stride) {
        int4 d = d4[i];
        int base = i << 2;
        if (d.x >= lo && d.x < hi) {
            int p = atomicAdd(&cursor[d.x], 1);
            packed[p] = make_int2(src[base + 0], __float_as_int(vals[base + 0]));
        }
        if (d.y >= lo && d.y < hi) {
            int p = atomicAdd(&cursor[d.y], 1);
            packed[p] = make_int2(src[base + 1], __float_as_int(vals[base + 1]));
        }
        if (d.z >= lo && d.z < hi) {
            int p = atomicAdd(&cursor[d.z], 1);
            packed[p] = make_int2(src[base + 2], __float_as_int(vals[base + 2]));
        }
        if (d.w >= lo && d.w < hi) {
            int p = atomicAdd(&cursor[d.w], 1);
            packed[p] = make_int2(src[base + 3], __float_as_int(vals[base + 3]));
        }
    }
    for (int i = (n4 << 2) + blockIdx.x * blockDim.x + threadIdx.x; i < n; i += stride) {
        int d = dst[i];
        if (d >= lo && d < hi) {
            int p = atomicAdd(&cursor[d], 1);
            packed[p] = make_int2(src[i], __float_as_int(vals[i]));
        }
    }
}

// ---------------------------------------------------------------------------
// SpMM gather: 16 lanes per dst node (float4 per lane = 64 dims), 4 nodes
// per wave. No shuffles, no cross-lane reduce; 4 independent 256B gathers
// in flight per wave-iteration. acc += fused into the epilogue.
// ---------------------------------------------------------------------------
__global__ __launch_bounds__(256) void spmm_gather(
        const int* __restrict__ row_ptr, const int2* __restrict__ packed,
        const float* __restrict__ x, float* __restrict__ y,
        float* __restrict__ acc) {
    int lane16  = threadIdx.x & 15;
    int group   = (int)((blockIdx.x * blockDim.x + threadIdx.x) >> 4);
    int ngroups = (int)((gridDim.x * blockDim.x) >> 4);
    const float4* x4 = (const float4*)x;
    float4* y4 = (float4*)y;
    float4* a4 = (float4*)acc;

    for (int node = group; node < N_NODES; node += ngroups) {
        int beg = row_ptr[node];
        int end = row_ptr[node + 1];
        float4 r = make_float4(0.f, 0.f, 0.f, 0.f);
        int e = beg;
        for (; e + 2 <= end; e += 2) {
            int2 pa = packed[e];
            int2 pb = packed[e + 1];
            float va = __int_as_float(pa.y);
            float vb = __int_as_float(pb.y);
            float4 xa = x4[(size_t)pa.x * 16 + lane16];
            float4 xb = x4[(size_t)pb.x * 16 + lane16];
            r.x += va * xa.x; r.y += va * xa.y; r.z += va * xa.z; r.w += va * xa.w;
            r.x += vb * xb.x; r.y += vb * xb.y; r.z += vb * xb.z; r.w += vb * xb.w;
        }
        if (e < end) {
            int2 pa = packed[e];
            float va = __int_as_float(pa.y);
            float4 xa = x4[(size_t)pa.x * 16 + lane16];
            r.x += va * xa.x; r.y += va * xa.y; r.z += va * xa.z; r.w += va * xa.w;
        }
        size_t o = (size_t)node * 16 + lane16;
        float4 a = a4[o];
        y4[o] = r;
        a.x += r.x; a.y += r.y; a.z += r.z; a.w += r.w;
        a4[o] = a;
    }
}

// ---------------------------------------------------------------------------
// ratings = sigmoid( (acc[users]/4) @ (acc[100000+items]/4)^T )
// ---------------------------------------------------------------------------
__global__ __launch_bounds__(256) void rating_kernel(
        const float* __restrict__ acc, const int* __restrict__ users,
        const int* __restrict__ items, float* __restrict__ out) {
    __shared__ float U[64][65];
    __shared__ float T[64][65];
    int bj = blockIdx.x;
    int bi = blockIdx.y;
    int t  = threadIdx.x;

    for (int idx = t; idx < 64 * 64; idx += 256) {
        int r = idx >> 6, k = idx & 63;
        int u = users[bi * 64 + r];
        U[r][k] = acc[(size_t)u * DIM + k] * 0.25f;
    }
    for (int idx = t; idx < 64 * 64; idx += 256) {
        int r = idx >> 6, k = idx & 63;
        int jg = bj * 64 + r;
        float v = 0.0f;
        if (jg < N_QI) {
            int it = items[jg];
            v = acc[((size_t)(NUM_USERS + it)) * DIM + k] * 0.25f;
        }
        T[r][k] = v;
    }
    __syncthreads();

    int tr = t >> 4, tc = t & 15;
    float c[4][4] = {};
    #pragma unroll
    for (int k = 0; k < 64; ++k) {
        float ua[4], tb[4];
        #pragma unroll
        for (int a = 0; a < 4; ++a) ua[a] = U[tr * 4 + a][k];
        #pragma unroll
        for (int b = 0; b < 4; ++b) tb[b] = T[tc * 4 + b][k];
        #pragma unroll
        for (int a = 0; a < 4; ++a)
            #pragma unroll
            for (int b = 0; b < 4; ++b)
                c[a][b] += ua[a] * tb[b];
    }

    #pragma unroll
    for (int a = 0; a < 4; ++a) {
        int i = bi * 64 + tr * 4 + a;
        int j = bj * 64 + tc * 4;
        if (j < N_QI) {
            float4 r;
            r.x = 1.0f / (1.0f + __expf(-c[a][0]));
            r.y = 1.0f / (1.0f + __expf(-c[a][1]));
            r.z = 1.0f / (1.0f + __expf(-c[a][2]));
            r.w = 1.0f / (1.0f + __expf(-c[a][3]));
            *(float4*)&out[(size_t)i * N_QI + j] = r;
        }
    }
}

// ---------------------------------------------------------------------------
extern "C" void kernel_launch(void* const* d_in, const int* in_sizes, int n_in,
                              void* d_out, int out_size, void* d_ws, size_t ws_size,
                              hipStream_t stream) {
    const float* user_emb  = (const float*)d_in[0];
    const float* item_emb  = (const float*)d_in[1];
    const int*   edge_src  = (const int*)d_in[2];
    const int*   edge_dst  = (const int*)d_in[3];
    const float* edge_vals = (const float*)d_in[4];
    const int*   users     = (const int*)d_in[5];
    const int*   items     = (const int*)d_in[6];
    float*       out       = (float*)d_out;
    int n_edges = in_sizes[2];

    const size_t nodeElems = (size_t)N_NODES * DIM;   // 9.6M floats

    float* acc    = (float*)d_ws;                     // 38.4 MB
    float* hA     = acc + nodeElems;                  // 38.4 MB
    float* hB     = hA + nodeElems;                   // 38.4 MB
    int2*  packed = (int2*)(hB + nodeElems);          // 38.4 MB (4.8M int2)
    int*   row_ptr = (int*)(packed + n_edges);        // 150001 ints
    int*   deg     = row_ptr + (N_NODES + 1);         // 150000 ints
    int*   cursor  = deg + N_NODES;                   // 150000 ints

    // --- CSR build (amortized over 3 layers) ---
    (void)hipMemsetAsync(deg, 0, (size_t)N_NODES * sizeof(int), stream);
    init_nodes<<<2048, 256, 0, stream>>>(user_emb, item_emb, acc, hA);
    hist_kernel<<<2048, 256, 0, stream>>>(edge_dst, deg, n_edges);
    scan_kernel<<<1, 1024, 0, stream>>>(deg, row_ptr, cursor);
    const int span = (N_NODES + N_SCATTER_PASSES - 1) / N_SCATTER_PASSES; // 18750
    for (int p = 0; p < N_SCATTER_PASSES; ++p) {
        int lo = p * span;
        int hi = lo + span; if (hi > N_NODES) hi = N_NODES;
        scatter_kernel<<<2048, 256, 0, stream>>>(edge_src, edge_dst, edge_vals,
                                                 cursor, packed, n_edges, lo, hi);
    }

    // --- 3 propagation layers, acc += fused ---
    float* cur = hA;
    float* nxt = hB;
    for (int l = 0; l < N_LAYERS; ++l) {
        spmm_gather<<<2048, 256, 0, stream>>>(row_ptr, packed, cur, nxt, acc);
        float* tmp = cur; cur = nxt; nxt = tmp;
    }

    // --- ratings ---
    dim3 grid((N_QI + 63) / 64, N_QU / 64);
    rating_kernel<<<grid, 256, 0, stream>>>(acc, users, items, out);
}

// Round 6
// 1359.480 us; speedup vs baseline: 2.7062x; 1.2344x over previous
//
#include <hip/hip_runtime.h>
#include <hip/hip_bf16.h>

#define NUM_USERS 100000
#define NUM_ITEMS 50000
#define N_NODES   150000
#define DIM       64
#define N_LAYERS  3
#define N_QU      1024
#define N_QI      20000
#define N_SCATTER_PASSES 8

#define SCAN_CHUNK 1024
#define SCAN_NB ((N_NODES + SCAN_CHUNK - 1) / SCAN_CHUNK)   // 147 blocks

// ---------------------------------------------------------------------------
// init: acc = h = concat(user_emb, item_emb), vectorized float4
// ---------------------------------------------------------------------------
__global__ void init_nodes(const float* __restrict__ ue, const float* __restrict__ ie,
                           float* __restrict__ acc, float* __restrict__ h) {
    const size_t n4   = (size_t)N_NODES * DIM / 4;
    const size_t uend = (size_t)NUM_USERS * DIM / 4;
    const float4* ue4 = (const float4*)ue;
    const float4* ie4 = (const float4*)ie;
    float4* acc4 = (float4*)acc;
    float4* h4   = (float4*)h;
    size_t stride = (size_t)gridDim.x * blockDim.x;
    for (size_t i = (size_t)blockIdx.x * blockDim.x + threadIdx.x; i < n4; i += stride) {
        float4 v = (i < uend) ? ue4[i] : ie4[i - uend];
        acc4[i] = v;
        h4[i]   = v;
    }
}

// ---------------------------------------------------------------------------
// CSR build step 1: degree histogram (int4-vectorized edge reads)
// ---------------------------------------------------------------------------
__global__ void hist_kernel(const int* __restrict__ dst, int* __restrict__ deg, int n) {
    int stride = gridDim.x * blockDim.x;
    int n4 = n >> 2;
    const int4* d4 = (const int4*)dst;
    for (int i = blockIdx.x * blockDim.x + threadIdx.x; i < n4; i += stride) {
        int4 d = d4[i];
        atomicAdd(&deg[d.x], 1);
        atomicAdd(&deg[d.y], 1);
        atomicAdd(&deg[d.z], 1);
        atomicAdd(&deg[d.w], 1);
    }
    for (int i = (n4 << 2) + blockIdx.x * blockDim.x + threadIdx.x; i < n; i += stride)
        atomicAdd(&deg[dst[i]], 1);
}

// ---------------------------------------------------------------------------
// CSR scan, phase 1: per-block (1024-node chunk) sum -> partials[b]
// ---------------------------------------------------------------------------
__global__ __launch_bounds__(256) void csr_partial(const int* __restrict__ deg,
                                                   int* __restrict__ partials) {
    int b = blockIdx.x, t = threadIdx.x;
    int base = b * SCAN_CHUNK + t * 4;
    int s = 0;
    #pragma unroll
    for (int j = 0; j < 4; ++j) {
        int i = base + j;
        if (i < N_NODES) s += deg[i];
    }
    __shared__ int red[4];
    for (int off = 32; off > 0; off >>= 1) s += __shfl_down(s, off);
    if ((t & 63) == 0) red[t >> 6] = s;
    __syncthreads();
    if (t == 0) partials[b] = red[0] + red[1] + red[2] + red[3];
}

// ---------------------------------------------------------------------------
// CSR scan, phase 2: exclusive scan of the 147 block partials (one tiny block)
// ---------------------------------------------------------------------------
__global__ __launch_bounds__(256) void csr_scan_partials(const int* __restrict__ partials,
                                                         int* __restrict__ bofs) {
    __shared__ int sh[256];
    int t = threadIdx.x;
    int v = (t < SCAN_NB) ? partials[t] : 0;
    sh[t] = v;
    __syncthreads();
    int x = v;
    for (int off = 1; off < 256; off <<= 1) {
        int y = (t >= off) ? sh[t - off] : 0;
        __syncthreads();
        x += y;
        sh[t] = x;
        __syncthreads();
    }
    if (t < SCAN_NB) bofs[t] = x - v;   // exclusive
}

// ---------------------------------------------------------------------------
// CSR scan, phase 3: local exclusive scan + block offset -> row_ptr, cursor
// ---------------------------------------------------------------------------
__global__ __launch_bounds__(256) void csr_final(const int* __restrict__ deg,
        const int* __restrict__ bofs, int* __restrict__ row_ptr,
        int* __restrict__ cursor) {
    __shared__ int sh[256];
    int b = blockIdx.x, t = threadIdx.x;
    int base = b * SCAN_CHUNK + t * 4;
    int d[4];
    int s = 0;
    #pragma unroll
    for (int j = 0; j < 4; ++j) {
        int i = base + j;
        d[j] = (i < N_NODES) ? deg[i] : 0;
        s += d[j];
    }
    sh[t] = s;
    __syncthreads();
    int x = s;
    for (int off = 1; off < 256; off <<= 1) {
        int y = (t >= off) ? sh[t - off] : 0;
        __syncthreads();
        x += y;
        sh[t] = x;
        __syncthreads();
    }
    int run = bofs[b] + x - s;   // exclusive prefix for this thread's 4 nodes
    #pragma unroll
    for (int j = 0; j < 4; ++j) {
        int i = base + j;
        if (i < N_NODES) { row_ptr[i] = run; cursor[i] = run; run += d[j]; }
    }
    if (b == (int)gridDim.x - 1 && t == 255) row_ptr[N_NODES] = run;   // = n_edges
}

// ---------------------------------------------------------------------------
// CSR build: range-partitioned scatter (write window stays L2-resident)
// ---------------------------------------------------------------------------
__global__ void scatter_kernel(const int* __restrict__ src, const int* __restrict__ dst,
        const float* __restrict__ vals, int* __restrict__ cursor,
        int2* __restrict__ packed, int n, int lo, int hi) {
    int stride = gridDim.x * blockDim.x;
    int n4 = n >> 2;
    const int4* d4 = (const int4*)dst;
    for (int i = blockIdx.x * blockDim.x + threadIdx.x; i < n4; i += stride) {
        int4 d = d4[i];
        int base = i << 2;
        if (d.x >= lo && d.x < hi) {
            int p = atomicAdd(&cursor[d.x], 1);
            packed[p] = make_int2(src[base + 0], __float_as_int(vals[base + 0]));
        }
        if (d.y >= lo && d.y < hi) {
            int p = atomicAdd(&cursor[d.y], 1);
            packed[p] = make_int2(src[base + 1], __float_as_int(vals[base + 1]));
        }
        if (d.z >= lo && d.z < hi) {
            int p = atomicAdd(&cursor[d.z], 1);
            packed[p] = make_int2(src[base + 2], __float_as_int(vals[base + 2]));
        }
        if (d.w >= lo && d.w < hi) {
            int p = atomicAdd(&cursor[d.w], 1);
            packed[p] = make_int2(src[base + 3], __float_as_int(vals[base + 3]));
        }
    }
    for (int i = (n4 << 2) + blockIdx.x * blockDim.x + threadIdx.x; i < n; i += stride) {
        int d = dst[i];
        if (d >= lo && d < hi) {
            int p = atomicAdd(&cursor[d], 1);
            packed[p] = make_int2(src[i], __float_as_int(vals[i]));
        }
    }
}

// ---------------------------------------------------------------------------
// SpMM gather: 16 lanes per dst node (float4 per lane = 64 dims), 4 nodes
// per wave. No shuffles, no cross-lane reduce. acc += fused.
// ---------------------------------------------------------------------------
__global__ __launch_bounds__(256) void spmm_gather(
        const int* __restrict__ row_ptr, const int2* __restrict__ packed,
        const float* __restrict__ x, float* __restrict__ y,
        float* __restrict__ acc) {
    int lane16  = threadIdx.x & 15;
    int group   = (int)((blockIdx.x * blockDim.x + threadIdx.x) >> 4);
    int ngroups = (int)((gridDim.x * blockDim.x) >> 4);
    const float4* x4 = (const float4*)x;
    float4* y4 = (float4*)y;
    float4* a4 = (float4*)acc;

    for (int node = group; node < N_NODES; node += ngroups) {
        int beg = row_ptr[node];
        int end = row_ptr[node + 1];
        float4 r = make_float4(0.f, 0.f, 0.f, 0.f);
        int e = beg;
        for (; e + 2 <= end; e += 2) {
            int2 pa = packed[e];
            int2 pb = packed[e + 1];
            float va = __int_as_float(pa.y);
            float vb = __int_as_float(pb.y);
            float4 xa = x4[(size_t)pa.x * 16 + lane16];
            float4 xb = x4[(size_t)pb.x * 16 + lane16];
            r.x += va * xa.x; r.y += va * xa.y; r.z += va * xa.z; r.w += va * xa.w;
            r.x += vb * xb.x; r.y += vb * xb.y; r.z += vb * xb.z; r.w += vb * xb.w;
        }
        if (e < end) {
            int2 pa = packed[e];
            float va = __int_as_float(pa.y);
            float4 xa = x4[(size_t)pa.x * 16 + lane16];
            r.x += va * xa.x; r.y += va * xa.y; r.z += va * xa.z; r.w += va * xa.w;
        }
        size_t o = (size_t)node * 16 + lane16;
        float4 a = a4[o];
        y4[o] = r;
        a.x += r.x; a.y += r.y; a.z += r.z; a.w += r.w;
        a4[o] = a;
    }
}

// ---------------------------------------------------------------------------
// ratings = sigmoid( (acc[users]/4) @ (acc[100000+items]/4)^T )
// ---------------------------------------------------------------------------
__global__ __launch_bounds__(256) void rating_kernel(
        const float* __restrict__ acc, const int* __restrict__ users,
        const int* __restrict__ items, float* __restrict__ out) {
    __shared__ float U[64][65];
    __shared__ float T[64][65];
    int bj = blockIdx.x;
    int bi = blockIdx.y;
    int t  = threadIdx.x;

    for (int idx = t; idx < 64 * 64; idx += 256) {
        int r = idx >> 6, k = idx & 63;
        int u = users[bi * 64 + r];
        U[r][k] = acc[(size_t)u * DIM + k] * 0.25f;
    }
    for (int idx = t; idx < 64 * 64; idx += 256) {
        int r = idx >> 6, k = idx & 63;
        int jg = bj * 64 + r;
        float v = 0.0f;
        if (jg < N_QI) {
            int it = items[jg];
            v = acc[((size_t)(NUM_USERS + it)) * DIM + k] * 0.25f;
        }
        T[r][k] = v;
    }
    __syncthreads();

    int tr = t >> 4, tc = t & 15;
    float c[4][4] = {};
    #pragma unroll
    for (int k = 0; k < 64; ++k) {
        float ua[4], tb[4];
        #pragma unroll
        for (int a = 0; a < 4; ++a) ua[a] = U[tr * 4 + a][k];
        #pragma unroll
        for (int b = 0; b < 4; ++b) tb[b] = T[tc * 4 + b][k];
        #pragma unroll
        for (int a = 0; a < 4; ++a)
            #pragma unroll
            for (int b = 0; b < 4; ++b)
                c[a][b] += ua[a] * tb[b];
    }

    #pragma unroll
    for (int a = 0; a < 4; ++a) {
        int i = bi * 64 + tr * 4 + a;
        int j = bj * 64 + tc * 4;
        if (j < N_QI) {
            float4 r;
            r.x = 1.0f / (1.0f + __expf(-c[a][0]));
            r.y = 1.0f / (1.0f + __expf(-c[a][1]));
            r.z = 1.0f / (1.0f + __expf(-c[a][2]));
            r.w = 1.0f / (1.0f + __expf(-c[a][3]));
            *(float4*)&out[(size_t)i * N_QI + j] = r;
        }
    }
}

// ---------------------------------------------------------------------------
extern "C" void kernel_launch(void* const* d_in, const int* in_sizes, int n_in,
                              void* d_out, int out_size, void* d_ws, size_t ws_size,
                              hipStream_t stream) {
    const float* user_emb  = (const float*)d_in[0];
    const float* item_emb  = (const float*)d_in[1];
    const int*   edge_src  = (const int*)d_in[2];
    const int*   edge_dst  = (const int*)d_in[3];
    const float* edge_vals = (const float*)d_in[4];
    const int*   users     = (const int*)d_in[5];
    const int*   items     = (const int*)d_in[6];
    float*       out       = (float*)d_out;
    int n_edges = in_sizes[2];

    const size_t nodeElems = (size_t)N_NODES * DIM;   // 9.6M floats

    float* acc     = (float*)d_ws;                    // 38.4 MB
    float* hA      = acc + nodeElems;                 // 38.4 MB
    float* hB      = hA + nodeElems;                  // 38.4 MB
    int2*  packed  = (int2*)(hB + nodeElems);         // 38.4 MB (4.8M int2)
    int*   row_ptr = (int*)(packed + n_edges);        // 150001 ints
    int*   deg     = row_ptr + (N_NODES + 1);         // 150000 ints
    int*   cursor  = deg + N_NODES;                   // 150000 ints
    int*   partials = cursor + N_NODES;               // 147 ints
    int*   bofs     = partials + SCAN_NB;             // 147 ints

    // --- CSR build (amortized over 3 layers) ---
    (void)hipMemsetAsync(deg, 0, (size_t)N_NODES * sizeof(int), stream);
    init_nodes<<<2048, 256, 0, stream>>>(user_emb, item_emb, acc, hA);
    hist_kernel<<<2048, 256, 0, stream>>>(edge_dst, deg, n_edges);
    csr_partial<<<SCAN_NB, 256, 0, stream>>>(deg, partials);
    csr_scan_partials<<<1, 256, 0, stream>>>(partials, bofs);
    csr_final<<<SCAN_NB, 256, 0, stream>>>(deg, bofs, row_ptr, cursor);
    const int span = (N_NODES + N_SCATTER_PASSES - 1) / N_SCATTER_PASSES; // 18750
    for (int p = 0; p < N_SCATTER_PASSES; ++p) {
        int lo = p * span;
        int hi = lo + span; if (hi > N_NODES) hi = N_NODES;
        scatter_kernel<<<2048, 256, 0, stream>>>(edge_src, edge_dst, edge_vals,
                                                 cursor, packed, n_edges, lo, hi);
    }

    // --- 3 propagation layers, acc += fused ---
    float* cur = hA;
    float* nxt = hB;
    for (int l = 0; l < N_LAYERS; ++l) {
        spmm_gather<<<2048, 256, 0, stream>>>(row_ptr, packed, cur, nxt, acc);
        float* tmp = cur; cur = nxt; nxt = tmp;
    }

    // --- ratings ---
    dim3 grid((N_QI + 63) / 64, N_QU / 64);
    rating_kernel<<<grid, 256, 0, stream>>>(acc, users, items, out);
}

// Round 7
// 1080.765 us; speedup vs baseline: 3.4042x; 1.2579x over previous
//
#include <hip/hip_runtime.h>
#include <hip/hip_bf16.h>

#define NUM_USERS 100000
#define NUM_ITEMS 50000
#define N_NODES   150000
#define DIM       64
#define N_LAYERS  3
#define N_QU      1024
#define N_QI      20000
#define N_SCATTER_PASSES 8

#define SCAN_CHUNK 1024
#define SCAN_NB ((N_NODES + SCAN_CHUNK - 1) / SCAN_CHUNK)   // 147 blocks

typedef __attribute__((ext_vector_type(8))) short bf16x8;
typedef __attribute__((ext_vector_type(4))) float f32x4;

__device__ __forceinline__ short f2bf(float x) {   // RNE float -> bf16 bits
    unsigned u = __float_as_uint(x);
    u += 0x7FFF + ((u >> 16) & 1);
    return (short)(u >> 16);
}

// ---------------------------------------------------------------------------
// init: acc = h = concat(user_emb, item_emb), vectorized float4
// ---------------------------------------------------------------------------
__global__ void init_nodes(const float* __restrict__ ue, const float* __restrict__ ie,
                           float* __restrict__ acc, float* __restrict__ h) {
    const size_t n4   = (size_t)N_NODES * DIM / 4;
    const size_t uend = (size_t)NUM_USERS * DIM / 4;
    const float4* ue4 = (const float4*)ue;
    const float4* ie4 = (const float4*)ie;
    float4* acc4 = (float4*)acc;
    float4* h4   = (float4*)h;
    size_t stride = (size_t)gridDim.x * blockDim.x;
    for (size_t i = (size_t)blockIdx.x * blockDim.x + threadIdx.x; i < n4; i += stride) {
        float4 v = (i < uend) ? ue4[i] : ie4[i - uend];
        acc4[i] = v;
        h4[i]   = v;
    }
}

// ---------------------------------------------------------------------------
// CSR build step 1: degree histogram (int4-vectorized edge reads)
// ---------------------------------------------------------------------------
__global__ void hist_kernel(const int* __restrict__ dst, int* __restrict__ deg, int n) {
    int stride = gridDim.x * blockDim.x;
    int n4 = n >> 2;
    const int4* d4 = (const int4*)dst;
    for (int i = blockIdx.x * blockDim.x + threadIdx.x; i < n4; i += stride) {
        int4 d = d4[i];
        atomicAdd(&deg[d.x], 1);
        atomicAdd(&deg[d.y], 1);
        atomicAdd(&deg[d.z], 1);
        atomicAdd(&deg[d.w], 1);
    }
    for (int i = (n4 << 2) + blockIdx.x * blockDim.x + threadIdx.x; i < n; i += stride)
        atomicAdd(&deg[dst[i]], 1);
}

// ---------------------------------------------------------------------------
// CSR scan, phase 1: per-block (1024-node chunk) sum -> partials[b]
// ---------------------------------------------------------------------------
__global__ __launch_bounds__(256) void csr_partial(const int* __restrict__ deg,
                                                   int* __restrict__ partials) {
    int b = blockIdx.x, t = threadIdx.x;
    int base = b * SCAN_CHUNK + t * 4;
    int s = 0;
    #pragma unroll
    for (int j = 0; j < 4; ++j) {
        int i = base + j;
        if (i < N_NODES) s += deg[i];
    }
    __shared__ int red[4];
    for (int off = 32; off > 0; off >>= 1) s += __shfl_down(s, off);
    if ((t & 63) == 0) red[t >> 6] = s;
    __syncthreads();
    if (t == 0) partials[b] = red[0] + red[1] + red[2] + red[3];
}

// ---------------------------------------------------------------------------
// CSR scan, phase 2: exclusive scan of the 147 block partials (one tiny block)
// ---------------------------------------------------------------------------
__global__ __launch_bounds__(256) void csr_scan_partials(const int* __restrict__ partials,
                                                         int* __restrict__ bofs) {
    __shared__ int sh[256];
    int t = threadIdx.x;
    int v = (t < SCAN_NB) ? partials[t] : 0;
    sh[t] = v;
    __syncthreads();
    int x = v;
    for (int off = 1; off < 256; off <<= 1) {
        int y = (t >= off) ? sh[t - off] : 0;
        __syncthreads();
        x += y;
        sh[t] = x;
        __syncthreads();
    }
    if (t < SCAN_NB) bofs[t] = x - v;   // exclusive
}

// ---------------------------------------------------------------------------
// CSR scan, phase 3: local exclusive scan + block offset -> row_ptr, cursor
// ---------------------------------------------------------------------------
__global__ __launch_bounds__(256) void csr_final(const int* __restrict__ deg,
        const int* __restrict__ bofs, int* __restrict__ row_ptr,
        int* __restrict__ cursor) {
    __shared__ int sh[256];
    int b = blockIdx.x, t = threadIdx.x;
    int base = b * SCAN_CHUNK + t * 4;
    int d[4];
    int s = 0;
    #pragma unroll
    for (int j = 0; j < 4; ++j) {
        int i = base + j;
        d[j] = (i < N_NODES) ? deg[i] : 0;
        s += d[j];
    }
    sh[t] = s;
    __syncthreads();
    int x = s;
    for (int off = 1; off < 256; off <<= 1) {
        int y = (t >= off) ? sh[t - off] : 0;
        __syncthreads();
        x += y;
        sh[t] = x;
        __syncthreads();
    }
    int run = bofs[b] + x - s;   // exclusive prefix for this thread's 4 nodes
    #pragma unroll
    for (int j = 0; j < 4; ++j) {
        int i = base + j;
        if (i < N_NODES) { row_ptr[i] = run; cursor[i] = run; run += d[j]; }
    }
    if (b == (int)gridDim.x - 1 && t == 255) row_ptr[N_NODES] = run;   // = n_edges
}

// ---------------------------------------------------------------------------
// CSR build: range-partitioned scatter (write window stays L2-resident)
// ---------------------------------------------------------------------------
__global__ void scatter_kernel(const int* __restrict__ src, const int* __restrict__ dst,
        const float* __restrict__ vals, int* __restrict__ cursor,
        int2* __restrict__ packed, int n, int lo, int hi) {
    int stride = gridDim.x * blockDim.x;
    int n4 = n >> 2;
    const int4* d4 = (const int4*)dst;
    for (int i = blockIdx.x * blockDim.x + threadIdx.x; i < n4; i += stride) {
        int4 d = d4[i];
        int base = i << 2;
        if (d.x >= lo && d.x < hi) {
            int p = atomicAdd(&cursor[d.x], 1);
            packed[p] = make_int2(src[base + 0], __float_as_int(vals[base + 0]));
        }
        if (d.y >= lo && d.y < hi) {
            int p = atomicAdd(&cursor[d.y], 1);
            packed[p] = make_int2(src[base + 1], __float_as_int(vals[base + 1]));
        }
        if (d.z >= lo && d.z < hi) {
            int p = atomicAdd(&cursor[d.z], 1);
            packed[p] = make_int2(src[base + 2], __float_as_int(vals[base + 2]));
        }
        if (d.w >= lo && d.w < hi) {
            int p = atomicAdd(&cursor[d.w], 1);
            packed[p] = make_int2(src[base + 3], __float_as_int(vals[base + 3]));
        }
    }
    for (int i = (n4 << 2) + blockIdx.x * blockDim.x + threadIdx.x; i < n; i += stride) {
        int d = dst[i];
        if (d >= lo && d < hi) {
            int p = atomicAdd(&cursor[d], 1);
            packed[p] = make_int2(src[i], __float_as_int(vals[i]));
        }
    }
}

// ---------------------------------------------------------------------------
// SpMM gather: 16 lanes per dst node (float4 per lane = 64 dims), 4 nodes
// per wave. No shuffles, no cross-lane reduce. acc += fused.
// ---------------------------------------------------------------------------
__global__ __launch_bounds__(256) void spmm_gather(
        const int* __restrict__ row_ptr, const int2* __restrict__ packed,
        const float* __restrict__ x, float* __restrict__ y,
        float* __restrict__ acc) {
    int lane16  = threadIdx.x & 15;
    int group   = (int)((blockIdx.x * blockDim.x + threadIdx.x) >> 4);
    int ngroups = (int)((gridDim.x * blockDim.x) >> 4);
    const float4* x4 = (const float4*)x;
    float4* y4 = (float4*)y;
    float4* a4 = (float4*)acc;

    for (int node = group; node < N_NODES; node += ngroups) {
        int beg = row_ptr[node];
        int end = row_ptr[node + 1];
        float4 r = make_float4(0.f, 0.f, 0.f, 0.f);
        int e = beg;
        for (; e + 2 <= end; e += 2) {
            int2 pa = packed[e];
            int2 pb = packed[e + 1];
            float va = __int_as_float(pa.y);
            float vb = __int_as_float(pb.y);
            float4 xa = x4[(size_t)pa.x * 16 + lane16];
            float4 xb = x4[(size_t)pb.x * 16 + lane16];
            r.x += va * xa.x; r.y += va * xa.y; r.z += va * xa.z; r.w += va * xa.w;
            r.x += vb * xb.x; r.y += vb * xb.y; r.z += vb * xb.z; r.w += vb * xb.w;
        }
        if (e < end) {
            int2 pa = packed[e];
            float va = __int_as_float(pa.y);
            float4 xa = x4[(size_t)pa.x * 16 + lane16];
            r.x += va * xa.x; r.y += va * xa.y; r.z += va * xa.z; r.w += va * xa.w;
        }
        size_t o = (size_t)node * 16 + lane16;
        float4 a = a4[o];
        y4[o] = r;
        a.x += r.x; a.y += r.y; a.z += r.z; a.w += r.w;
        a4[o] = a;
    }
}

// ---------------------------------------------------------------------------
// ratings = sigmoid( (acc[users]/4) @ (acc[100000+items]/4)^T ) via bf16 MFMA.
// Block: 256 threads = 4 waves; tile 64 users x 256 items; wave w owns the
// 64x64 item strip [w*64, w*64+64). LDS tiles row-major bf16 with row stride
// 72 shorts (144 B -> 4-bank shift per row, 2-way conflict = free).
// Fragment layout (verified m89/m92): A/B lane l holds row (l&15), k
// (l>>4)*8..+8 contiguous; C/D: col = lane&15, row = (lane>>4)*4 + reg.
// ---------------------------------------------------------------------------
__global__ __launch_bounds__(256) void rating_mfma(
        const float* __restrict__ acc, const int* __restrict__ users,
        const int* __restrict__ items, float* __restrict__ out) {
    __shared__ short Ut[64 * 72];     //  9216 B
    __shared__ short Tt[256 * 72];    // 36864 B
    const int bj = blockIdx.x;        // item tile (256 wide)
    const int bi = blockIdx.y;        // user tile (64 wide)
    const int tid = threadIdx.x;

    // --- stage U: 64 rows x 64 cols, each thread does 16 floats ---
    {
        int r = tid >> 2, c16 = (tid & 3) * 16;
        int u = users[bi * 64 + r];
        const float4* s = (const float4*)&acc[(size_t)u * DIM + c16];
        bf16x8 lo, hi;
        #pragma unroll
        for (int k = 0; k < 2; ++k) {
            float4 v = s[k];
            lo[k*4+0] = f2bf(v.x * 0.25f); lo[k*4+1] = f2bf(v.y * 0.25f);
            lo[k*4+2] = f2bf(v.z * 0.25f); lo[k*4+3] = f2bf(v.w * 0.25f);
        }
        #pragma unroll
        for (int k = 0; k < 2; ++k) {
            float4 v = s[2 + k];
            hi[k*4+0] = f2bf(v.x * 0.25f); hi[k*4+1] = f2bf(v.y * 0.25f);
            hi[k*4+2] = f2bf(v.z * 0.25f); hi[k*4+3] = f2bf(v.w * 0.25f);
        }
        *(bf16x8*)&Ut[r * 72 + c16]     = lo;
        *(bf16x8*)&Ut[r * 72 + c16 + 8] = hi;
    }

    // --- stage T: 256 rows x 64 cols, 4 passes ---
    #pragma unroll
    for (int p = 0; p < 4; ++p) {
        int r = (tid >> 2) + p * 64, c16 = (tid & 3) * 16;
        int jg = bj * 256 + r;
        bf16x8 lo = (bf16x8)(short)0, hi = (bf16x8)(short)0;
        if (jg < N_QI) {
            int it = items[jg];
            const float4* s = (const float4*)&acc[((size_t)(NUM_USERS + it)) * DIM + c16];
            #pragma unroll
            for (int k = 0; k < 2; ++k) {
                float4 v = s[k];
                lo[k*4+0] = f2bf(v.x * 0.25f); lo[k*4+1] = f2bf(v.y * 0.25f);
                lo[k*4+2] = f2bf(v.z * 0.25f); lo[k*4+3] = f2bf(v.w * 0.25f);
            }
            #pragma unroll
            for (int k = 0; k < 2; ++k) {
                float4 v = s[2 + k];
                hi[k*4+0] = f2bf(v.x * 0.25f); hi[k*4+1] = f2bf(v.y * 0.25f);
                hi[k*4+2] = f2bf(v.z * 0.25f); hi[k*4+3] = f2bf(v.w * 0.25f);
            }
        }
        *(bf16x8*)&Tt[r * 72 + c16]     = lo;
        *(bf16x8*)&Tt[r * 72 + c16 + 8] = hi;
    }
    __syncthreads();

    // --- MFMA: wave wv computes 64x64 (4x4 fragments of 16x16, K=64) ---
    const int wv = tid >> 6, lane = tid & 63;
    const int lr = lane & 15, kq = lane >> 4;

    f32x4 c[4][4];
    #pragma unroll
    for (int mr = 0; mr < 4; ++mr)
        #pragma unroll
        for (int nr = 0; nr < 4; ++nr)
            c[mr][nr] = (f32x4)(0.0f);

    #pragma unroll
    for (int kb = 0; kb < 2; ++kb) {
        bf16x8 a[4], b[4];
        #pragma unroll
        for (int mr = 0; mr < 4; ++mr)
            a[mr] = *(const bf16x8*)&Ut[(mr * 16 + lr) * 72 + (kb * 4 + kq) * 8];
        #pragma unroll
        for (int nr = 0; nr < 4; ++nr)
            b[nr] = *(const bf16x8*)&Tt[(wv * 64 + nr * 16 + lr) * 72 + (kb * 4 + kq) * 8];
        #pragma unroll
        for (int mr = 0; mr < 4; ++mr)
            #pragma unroll
            for (int nr = 0; nr < 4; ++nr)
                c[mr][nr] = __builtin_amdgcn_mfma_f32_16x16x32_bf16(a[mr], b[nr], c[mr][nr], 0, 0, 0);
    }

    // --- epilogue: sigmoid + guarded store ---
    #pragma unroll
    for (int mr = 0; mr < 4; ++mr) {
        int rowg = bi * 64 + mr * 16 + kq * 4;
        #pragma unroll
        for (int nr = 0; nr < 4; ++nr) {
            int colg = bj * 256 + wv * 64 + nr * 16 + lr;
            if (colg < N_QI) {
                #pragma unroll
                for (int q = 0; q < 4; ++q) {
                    float z = c[mr][nr][q];
                    out[(size_t)(rowg + q) * N_QI + colg] = 1.0f / (1.0f + __expf(-z));
                }
            }
        }
    }
}

// ---------------------------------------------------------------------------
extern "C" void kernel_launch(void* const* d_in, const int* in_sizes, int n_in,
                              void* d_out, int out_size, void* d_ws, size_t ws_size,
                              hipStream_t stream) {
    const float* user_emb  = (const float*)d_in[0];
    const float* item_emb  = (const float*)d_in[1];
    const int*   edge_src  = (const int*)d_in[2];
    const int*   edge_dst  = (const int*)d_in[3];
    const float* edge_vals = (const float*)d_in[4];
    const int*   users     = (const int*)d_in[5];
    const int*   items     = (const int*)d_in[6];
    float*       out       = (float*)d_out;
    int n_edges = in_sizes[2];

    const size_t nodeElems = (size_t)N_NODES * DIM;   // 9.6M floats

    float* acc     = (float*)d_ws;                    // 38.4 MB
    float* hA      = acc + nodeElems;                 // 38.4 MB
    float* hB      = hA + nodeElems;                  // 38.4 MB
    int2*  packed  = (int2*)(hB + nodeElems);         // 38.4 MB (4.8M int2)
    int*   row_ptr = (int*)(packed + n_edges);        // 150001 ints
    int*   deg     = row_ptr + (N_NODES + 1);         // 150000 ints
    int*   cursor  = deg + N_NODES;                   // 150000 ints
    int*   partials = cursor + N_NODES;               // 147 ints
    int*   bofs     = partials + SCAN_NB;             // 147 ints

    // --- CSR build (amortized over 3 layers) ---
    (void)hipMemsetAsync(deg, 0, (size_t)N_NODES * sizeof(int), stream);
    init_nodes<<<2048, 256, 0, stream>>>(user_emb, item_emb, acc, hA);
    hist_kernel<<<2048, 256, 0, stream>>>(edge_dst, deg, n_edges);
    csr_partial<<<SCAN_NB, 256, 0, stream>>>(deg, partials);
    csr_scan_partials<<<1, 256, 0, stream>>>(partials, bofs);
    csr_final<<<SCAN_NB, 256, 0, stream>>>(deg, bofs, row_ptr, cursor);
    const int span = (N_NODES + N_SCATTER_PASSES - 1) / N_SCATTER_PASSES; // 18750
    for (int p = 0; p < N_SCATTER_PASSES; ++p) {
        int lo = p * span;
        int hi = lo + span; if (hi > N_NODES) hi = N_NODES;
        scatter_kernel<<<2048, 256, 0, stream>>>(edge_src, edge_dst, edge_vals,
                                                 cursor, packed, n_edges, lo, hi);
    }

    // --- 3 propagation layers, acc += fused ---
    float* cur = hA;
    float* nxt = hB;
    for (int l = 0; l < N_LAYERS; ++l) {
        spmm_gather<<<2048, 256, 0, stream>>>(row_ptr, packed, cur, nxt, acc);
        float* tmp = cur; cur = nxt; nxt = tmp;
    }

    // --- ratings ---
    dim3 grid((N_QI + 255) / 256, N_QU / 64);
    rating_mfma<<<grid, 256, 0, stream>>>(acc, users, items, out);
}

// Round 8
// 894.122 us; speedup vs baseline: 4.1148x; 1.2087x over previous
//
#include <hip/hip_runtime.h>
#include <hip/hip_bf16.h>

#define NUM_USERS 100000
#define NUM_ITEMS 50000
#define N_NODES   150000
#define DIM       64
#define N_LAYERS  3
#define N_QU      1024
#define N_QI      20000
#define N_SCATTER_PASSES 8
#define SLOTS     80

#define SCAN_CHUNK 1024
#define SCAN_NB ((N_NODES + SCAN_CHUNK - 1) / SCAN_CHUNK)   // 147 blocks

typedef __attribute__((ext_vector_type(8))) short bf16x8;
typedef __attribute__((ext_vector_type(4))) float f32x4;

__device__ __forceinline__ short f2bf(float x) {   // RNE float -> bf16 bits
    unsigned u = __float_as_uint(x);
    u += 0x7FFF + ((u >> 16) & 1);
    return (short)(u >> 16);
}

// ---------------------------------------------------------------------------
// init: acc = h = concat(user_emb, item_emb), vectorized float4
// ---------------------------------------------------------------------------
__global__ void init_nodes(const float* __restrict__ ue, const float* __restrict__ ie,
                           float* __restrict__ acc, float* __restrict__ h) {
    const size_t n4   = (size_t)N_NODES * DIM / 4;
    const size_t uend = (size_t)NUM_USERS * DIM / 4;
    const float4* ue4 = (const float4*)ue;
    const float4* ie4 = (const float4*)ie;
    float4* acc4 = (float4*)acc;
    float4* h4   = (float4*)h;
    size_t stride = (size_t)gridDim.x * blockDim.x;
    for (size_t i = (size_t)blockIdx.x * blockDim.x + threadIdx.x; i < n4; i += stride) {
        float4 v = (i < uend) ? ue4[i] : ie4[i - uend];
        acc4[i] = v;
        h4[i]   = v;
    }
}

// ===========================================================================
// BUCKET PATH (no histogram, no scan): slot = atomicAdd(cnt[dst]) directly.
// ===========================================================================

// range-partitioned bucket scatter: only dst in [lo,hi) this pass, so the
// write window stays cache-resident and lines fill densely.
__global__ void scatter_bucket(const int* __restrict__ src, const int* __restrict__ dst,
        const float* __restrict__ vals, int* __restrict__ cnt,
        int2* __restrict__ buckets, int n, int lo, int hi) {
    int stride = gridDim.x * blockDim.x;
    int n4 = n >> 2;
    const int4* d4 = (const int4*)dst;
    for (int i = blockIdx.x * blockDim.x + threadIdx.x; i < n4; i += stride) {
        int4 d = d4[i];
        int base = i << 2;
        if (d.x >= lo && d.x < hi) {
            int s = atomicAdd(&cnt[d.x], 1);
            if (s < SLOTS) buckets[(size_t)d.x * SLOTS + s] = make_int2(src[base + 0], __float_as_int(vals[base + 0]));
        }
        if (d.y >= lo && d.y < hi) {
            int s = atomicAdd(&cnt[d.y], 1);
            if (s < SLOTS) buckets[(size_t)d.y * SLOTS + s] = make_int2(src[base + 1], __float_as_int(vals[base + 1]));
        }
        if (d.z >= lo && d.z < hi) {
            int s = atomicAdd(&cnt[d.z], 1);
            if (s < SLOTS) buckets[(size_t)d.z * SLOTS + s] = make_int2(src[base + 2], __float_as_int(vals[base + 2]));
        }
        if (d.w >= lo && d.w < hi) {
            int s = atomicAdd(&cnt[d.w], 1);
            if (s < SLOTS) buckets[(size_t)d.w * SLOTS + s] = make_int2(src[base + 3], __float_as_int(vals[base + 3]));
        }
    }
    for (int i = (n4 << 2) + blockIdx.x * blockDim.x + threadIdx.x; i < n; i += stride) {
        int d = dst[i];
        if (d >= lo && d < hi) {
            int s = atomicAdd(&cnt[d], 1);
            if (s < SLOTS) buckets[(size_t)d * SLOTS + s] = make_int2(src[i], __float_as_int(vals[i]));
        }
    }
}

// bucket SpMM gather: 16 lanes per dst node, float4 per lane. y may be null
// (last layer: only acc is needed).
__global__ __launch_bounds__(256) void spmm_bucket(
        const int* __restrict__ cnt, const int2* __restrict__ buckets,
        const float* __restrict__ x, float* __restrict__ y,
        float* __restrict__ acc) {
    int lane16  = threadIdx.x & 15;
    int group   = (int)((blockIdx.x * blockDim.x + threadIdx.x) >> 4);
    int ngroups = (int)((gridDim.x * blockDim.x) >> 4);
    const float4* x4 = (const float4*)x;
    float4* y4 = (float4*)y;
    float4* a4 = (float4*)acc;

    for (int node = group; node < N_NODES; node += ngroups) {
        int m = cnt[node]; if (m > SLOTS) m = SLOTS;
        const int2* row = &buckets[(size_t)node * SLOTS];
        float4 r = make_float4(0.f, 0.f, 0.f, 0.f);
        int e = 0;
        for (; e + 2 <= m; e += 2) {
            int2 pa = row[e];
            int2 pb = row[e + 1];
            float va = __int_as_float(pa.y);
            float vb = __int_as_float(pb.y);
            float4 xa = x4[(size_t)pa.x * 16 + lane16];
            float4 xb = x4[(size_t)pb.x * 16 + lane16];
            r.x += va * xa.x; r.y += va * xa.y; r.z += va * xa.z; r.w += va * xa.w;
            r.x += vb * xb.x; r.y += vb * xb.y; r.z += vb * xb.z; r.w += vb * xb.w;
        }
        if (e < m) {
            int2 pa = row[e];
            float va = __int_as_float(pa.y);
            float4 xa = x4[(size_t)pa.x * 16 + lane16];
            r.x += va * xa.x; r.y += va * xa.y; r.z += va * xa.z; r.w += va * xa.w;
        }
        size_t o = (size_t)node * 16 + lane16;
        float4 a = a4[o];
        if (y4) y4[o] = r;
        a.x += r.x; a.y += r.y; a.z += r.z; a.w += r.w;
        a4[o] = a;
    }
}

// ===========================================================================
// CSR FALLBACK PATH (Round 7) — used when ws_size can't hold the buckets.
// ===========================================================================

__global__ void hist_kernel(const int* __restrict__ dst, int* __restrict__ deg, int n) {
    int stride = gridDim.x * blockDim.x;
    int n4 = n >> 2;
    const int4* d4 = (const int4*)dst;
    for (int i = blockIdx.x * blockDim.x + threadIdx.x; i < n4; i += stride) {
        int4 d = d4[i];
        atomicAdd(&deg[d.x], 1);
        atomicAdd(&deg[d.y], 1);
        atomicAdd(&deg[d.z], 1);
        atomicAdd(&deg[d.w], 1);
    }
    for (int i = (n4 << 2) + blockIdx.x * blockDim.x + threadIdx.x; i < n; i += stride)
        atomicAdd(&deg[dst[i]], 1);
}

__global__ __launch_bounds__(256) void csr_partial(const int* __restrict__ deg,
                                                   int* __restrict__ partials) {
    int b = blockIdx.x, t = threadIdx.x;
    int base = b * SCAN_CHUNK + t * 4;
    int s = 0;
    #pragma unroll
    for (int j = 0; j < 4; ++j) {
        int i = base + j;
        if (i < N_NODES) s += deg[i];
    }
    __shared__ int red[4];
    for (int off = 32; off > 0; off >>= 1) s += __shfl_down(s, off);
    if ((t & 63) == 0) red[t >> 6] = s;
    __syncthreads();
    if (t == 0) partials[b] = red[0] + red[1] + red[2] + red[3];
}

__global__ __launch_bounds__(256) void csr_scan_partials(const int* __restrict__ partials,
                                                         int* __restrict__ bofs) {
    __shared__ int sh[256];
    int t = threadIdx.x;
    int v = (t < SCAN_NB) ? partials[t] : 0;
    sh[t] = v;
    __syncthreads();
    int x = v;
    for (int off = 1; off < 256; off <<= 1) {
        int y = (t >= off) ? sh[t - off] : 0;
        __syncthreads();
        x += y;
        sh[t] = x;
        __syncthreads();
    }
    if (t < SCAN_NB) bofs[t] = x - v;
}

__global__ __launch_bounds__(256) void csr_final(const int* __restrict__ deg,
        const int* __restrict__ bofs, int* __restrict__ row_ptr,
        int* __restrict__ cursor) {
    __shared__ int sh[256];
    int b = blockIdx.x, t = threadIdx.x;
    int base = b * SCAN_CHUNK + t * 4;
    int d[4];
    int s = 0;
    #pragma unroll
    for (int j = 0; j < 4; ++j) {
        int i = base + j;
        d[j] = (i < N_NODES) ? deg[i] : 0;
        s += d[j];
    }
    sh[t] = s;
    __syncthreads();
    int x = s;
    for (int off = 1; off < 256; off <<= 1) {
        int y = (t >= off) ? sh[t - off] : 0;
        __syncthreads();
        x += y;
        sh[t] = x;
        __syncthreads();
    }
    int run = bofs[b] + x - s;
    #pragma unroll
    for (int j = 0; j < 4; ++j) {
        int i = base + j;
        if (i < N_NODES) { row_ptr[i] = run; cursor[i] = run; run += d[j]; }
    }
    if (b == (int)gridDim.x - 1 && t == 255) row_ptr[N_NODES] = run;
}

__global__ void scatter_kernel(const int* __restrict__ src, const int* __restrict__ dst,
        const float* __restrict__ vals, int* __restrict__ cursor,
        int2* __restrict__ packed, int n, int lo, int hi) {
    int stride = gridDim.x * blockDim.x;
    int n4 = n >> 2;
    const int4* d4 = (const int4*)dst;
    for (int i = blockIdx.x * blockDim.x + threadIdx.x; i < n4; i += stride) {
        int4 d = d4[i];
        int base = i << 2;
        if (d.x >= lo && d.x < hi) {
            int p = atomicAdd(&cursor[d.x], 1);
            packed[p] = make_int2(src[base + 0], __float_as_int(vals[base + 0]));
        }
        if (d.y >= lo && d.y < hi) {
            int p = atomicAdd(&cursor[d.y], 1);
            packed[p] = make_int2(src[base + 1], __float_as_int(vals[base + 1]));
        }
        if (d.z >= lo && d.z < hi) {
            int p = atomicAdd(&cursor[d.z], 1);
            packed[p] = make_int2(src[base + 2], __float_as_int(vals[base + 2]));
        }
        if (d.w >= lo && d.w < hi) {
            int p = atomicAdd(&cursor[d.w], 1);
            packed[p] = make_int2(src[base + 3], __float_as_int(vals[base + 3]));
        }
    }
    for (int i = (n4 << 2) + blockIdx.x * blockDim.x + threadIdx.x; i < n; i += stride) {
        int d = dst[i];
        if (d >= lo && d < hi) {
            int p = atomicAdd(&cursor[d], 1);
            packed[p] = make_int2(src[i], __float_as_int(vals[i]));
        }
    }
}

__global__ __launch_bounds__(256) void spmm_gather(
        const int* __restrict__ row_ptr, const int2* __restrict__ packed,
        const float* __restrict__ x, float* __restrict__ y,
        float* __restrict__ acc) {
    int lane16  = threadIdx.x & 15;
    int group   = (int)((blockIdx.x * blockDim.x + threadIdx.x) >> 4);
    int ngroups = (int)((gridDim.x * blockDim.x) >> 4);
    const float4* x4 = (const float4*)x;
    float4* y4 = (float4*)y;
    float4* a4 = (float4*)acc;

    for (int node = group; node < N_NODES; node += ngroups) {
        int beg = row_ptr[node];
        int end = row_ptr[node + 1];
        float4 r = make_float4(0.f, 0.f, 0.f, 0.f);
        int e = beg;
        for (; e + 2 <= end; e += 2) {
            int2 pa = packed[e];
            int2 pb = packed[e + 1];
            float va = __int_as_float(pa.y);
            float vb = __int_as_float(pb.y);
            float4 xa = x4[(size_t)pa.x * 16 + lane16];
            float4 xb = x4[(size_t)pb.x * 16 + lane16];
            r.x += va * xa.x; r.y += va * xa.y; r.z += va * xa.z; r.w += va * xa.w;
            r.x += vb * xb.x; r.y += vb * xb.y; r.z += vb * xb.z; r.w += vb * xb.w;
        }
        if (e < end) {
            int2 pa = packed[e];
            float va = __int_as_float(pa.y);
            float4 xa = x4[(size_t)pa.x * 16 + lane16];
            r.x += va * xa.x; r.y += va * xa.y; r.z += va * xa.z; r.w += va * xa.w;
        }
        size_t o = (size_t)node * 16 + lane16;
        float4 a = a4[o];
        y4[o] = r;
        a.x += r.x; a.y += r.y; a.z += r.z; a.w += r.w;
        a4[o] = a;
    }
}

// ---------------------------------------------------------------------------
// ratings = sigmoid( (acc[users]/4) @ (acc[100000+items]/4)^T ) via bf16 MFMA.
// ---------------------------------------------------------------------------
__global__ __launch_bounds__(256) void rating_mfma(
        const float* __restrict__ acc, const int* __restrict__ users,
        const int* __restrict__ items, float* __restrict__ out) {
    __shared__ short Ut[64 * 72];     //  9216 B
    __shared__ short Tt[256 * 72];    // 36864 B
    const int bj = blockIdx.x;        // item tile (256 wide)
    const int bi = blockIdx.y;        // user tile (64 wide)
    const int tid = threadIdx.x;

    {
        int r = tid >> 2, c16 = (tid & 3) * 16;
        int u = users[bi * 64 + r];
        const float4* s = (const float4*)&acc[(size_t)u * DIM + c16];
        bf16x8 lo, hi;
        #pragma unroll
        for (int k = 0; k < 2; ++k) {
            float4 v = s[k];
            lo[k*4+0] = f2bf(v.x * 0.25f); lo[k*4+1] = f2bf(v.y * 0.25f);
            lo[k*4+2] = f2bf(v.z * 0.25f); lo[k*4+3] = f2bf(v.w * 0.25f);
        }
        #pragma unroll
        for (int k = 0; k < 2; ++k) {
            float4 v = s[2 + k];
            hi[k*4+0] = f2bf(v.x * 0.25f); hi[k*4+1] = f2bf(v.y * 0.25f);
            hi[k*4+2] = f2bf(v.z * 0.25f); hi[k*4+3] = f2bf(v.w * 0.25f);
        }
        *(bf16x8*)&Ut[r * 72 + c16]     = lo;
        *(bf16x8*)&Ut[r * 72 + c16 + 8] = hi;
    }

    #pragma unroll
    for (int p = 0; p < 4; ++p) {
        int r = (tid >> 2) + p * 64, c16 = (tid & 3) * 16;
        int jg = bj * 256 + r;
        bf16x8 lo = (bf16x8)(short)0, hi = (bf16x8)(short)0;
        if (jg < N_QI) {
            int it = items[jg];
            const float4* s = (const float4*)&acc[((size_t)(NUM_USERS + it)) * DIM + c16];
            #pragma unroll
            for (int k = 0; k < 2; ++k) {
                float4 v = s[k];
                lo[k*4+0] = f2bf(v.x * 0.25f); lo[k*4+1] = f2bf(v.y * 0.25f);
                lo[k*4+2] = f2bf(v.z * 0.25f); lo[k*4+3] = f2bf(v.w * 0.25f);
            }
            #pragma unroll
            for (int k = 0; k < 2; ++k) {
                float4 v = s[2 + k];
                hi[k*4+0] = f2bf(v.x * 0.25f); hi[k*4+1] = f2bf(v.y * 0.25f);
                hi[k*4+2] = f2bf(v.z * 0.25f); hi[k*4+3] = f2bf(v.w * 0.25f);
            }
        }
        *(bf16x8*)&Tt[r * 72 + c16]     = lo;
        *(bf16x8*)&Tt[r * 72 + c16 + 8] = hi;
    }
    __syncthreads();

    const int wv = tid >> 6, lane = tid & 63;
    const int lr = lane & 15, kq = lane >> 4;

    f32x4 c[4][4];
    #pragma unroll
    for (int mr = 0; mr < 4; ++mr)
        #pragma unroll
        for (int nr = 0; nr < 4; ++nr)
            c[mr][nr] = (f32x4)(0.0f);

    #pragma unroll
    for (int kb = 0; kb < 2; ++kb) {
        bf16x8 a[4], b[4];
        #pragma unroll
        for (int mr = 0; mr < 4; ++mr)
            a[mr] = *(const bf16x8*)&Ut[(mr * 16 + lr) * 72 + (kb * 4 + kq) * 8];
        #pragma unroll
        for (int nr = 0; nr < 4; ++nr)
            b[nr] = *(const bf16x8*)&Tt[(wv * 64 + nr * 16 + lr) * 72 + (kb * 4 + kq) * 8];
        #pragma unroll
        for (int mr = 0; mr < 4; ++mr)
            #pragma unroll
            for (int nr = 0; nr < 4; ++nr)
                c[mr][nr] = __builtin_amdgcn_mfma_f32_16x16x32_bf16(a[mr], b[nr], c[mr][nr], 0, 0, 0);
    }

    #pragma unroll
    for (int mr = 0; mr < 4; ++mr) {
        int rowg = bi * 64 + mr * 16 + kq * 4;
        #pragma unroll
        for (int nr = 0; nr < 4; ++nr) {
            int colg = bj * 256 + wv * 64 + nr * 16 + lr;
            if (colg < N_QI) {
                #pragma unroll
                for (int q = 0; q < 4; ++q) {
                    float z = c[mr][nr][q];
                    out[(size_t)(rowg + q) * N_QI + colg] = 1.0f / (1.0f + __expf(-z));
                }
            }
        }
    }
}

// ---------------------------------------------------------------------------
extern "C" void kernel_launch(void* const* d_in, const int* in_sizes, int n_in,
                              void* d_out, int out_size, void* d_ws, size_t ws_size,
                              hipStream_t stream) {
    const float* user_emb  = (const float*)d_in[0];
    const float* item_emb  = (const float*)d_in[1];
    const int*   edge_src  = (const int*)d_in[2];
    const int*   edge_dst  = (const int*)d_in[3];
    const float* edge_vals = (const float*)d_in[4];
    const int*   users     = (const int*)d_in[5];
    const int*   items     = (const int*)d_in[6];
    float*       out       = (float*)d_out;
    int n_edges = in_sizes[2];

    const size_t nodeElems = (size_t)N_NODES * DIM;   // 9.6M floats

    float* acc = (float*)d_ws;
    float* hA  = acc + nodeElems;
    float* hB  = hA + nodeElems;

    // bucket path needs: 3 node buffers + cnt + buckets
    const size_t bucketBytes = (size_t)N_NODES * SLOTS * sizeof(int2);      // 96 MB
    const size_t needBucket  = 3 * nodeElems * sizeof(float)               // 115.2 MB
                             + (size_t)N_NODES * sizeof(int) + 256
                             + bucketBytes;
    const int span = (N_NODES + N_SCATTER_PASSES - 1) / N_SCATTER_PASSES;   // 18750

    if (ws_size >= needBucket) {
        // ---------------- bucket path: no histogram, no scan ----------------
        int*  cnt     = (int*)(hB + nodeElems);                 // 150000 ints (even)
        int2* buckets = (int2*)(cnt + N_NODES);                 // 12M int2

        (void)hipMemsetAsync(cnt, 0, (size_t)N_NODES * sizeof(int), stream);
        init_nodes<<<2048, 256, 0, stream>>>(user_emb, item_emb, acc, hA);
        for (int p = 0; p < N_SCATTER_PASSES; ++p) {
            int lo = p * span;
            int hi = lo + span; if (hi > N_NODES) hi = N_NODES;
            scatter_bucket<<<2048, 256, 0, stream>>>(edge_src, edge_dst, edge_vals,
                                                     cnt, buckets, n_edges, lo, hi);
        }

        float* cur = hA;
        float* nxt = hB;
        for (int l = 0; l < N_LAYERS; ++l) {
            float* yout = (l == N_LAYERS - 1) ? nullptr : nxt;   // last layer: acc only
            spmm_bucket<<<2048, 256, 0, stream>>>(cnt, buckets, cur, yout, acc);
            float* tmp = cur; cur = nxt; nxt = tmp;
        }
    } else {
        // ---------------- CSR fallback (Round 7) ----------------
        int2* packed   = (int2*)(hB + nodeElems);
        int*  row_ptr  = (int*)(packed + n_edges);
        int*  deg      = row_ptr + (N_NODES + 1);
        int*  cursor   = deg + N_NODES;
        int*  partials = cursor + N_NODES;
        int*  bofs     = partials + SCAN_NB;

        (void)hipMemsetAsync(deg, 0, (size_t)N_NODES * sizeof(int), stream);
        init_nodes<<<2048, 256, 0, stream>>>(user_emb, item_emb, acc, hA);
        hist_kernel<<<2048, 256, 0, stream>>>(edge_dst, deg, n_edges);
        csr_partial<<<SCAN_NB, 256, 0, stream>>>(deg, partials);
        csr_scan_partials<<<1, 256, 0, stream>>>(partials, bofs);
        csr_final<<<SCAN_NB, 256, 0, stream>>>(deg, bofs, row_ptr, cursor);
        for (int p = 0; p < N_SCATTER_PASSES; ++p) {
            int lo = p * span;
            int hi = lo + span; if (hi > N_NODES) hi = N_NODES;
            scatter_kernel<<<2048, 256, 0, stream>>>(edge_src, edge_dst, edge_vals,
                                                     cursor, packed, n_edges, lo, hi);
        }

        float* cur = hA;
        float* nxt = hB;
        for (int l = 0; l < N_LAYERS; ++l) {
            spmm_gather<<<2048, 256, 0, stream>>>(row_ptr, packed, cur, nxt, acc);
            float* tmp = cur; cur = nxt; nxt = tmp;
        }
    }

    // --- ratings ---
    dim3 grid((N_QI + 255) / 256, N_QU / 64);
    rating_mfma<<<grid, 256, 0, stream>>>(acc, users, items, out);
}